// Round 14
// baseline (4847.552 us; speedup 1.0000x reference)
//
#include <hip/hip_runtime.h>
#include <hip/hip_cooperative_groups.h>
#include <math.h>

namespace cg = cooperative_groups;

#define BB 64
#define TT 32
#define II 512
#define HH 1024
#define OO 512
#define NN 1024
#define MM 64
#define EPSF 1e-8f

// virtual GEMV row space (K=1024, all dot h):
//   [0,268)     gate rows  -> GY (activated)
//   [268,3340)  Whh rows   -> YT (+bhh)
//   [3340,3852) Who rows   -> outs[t-1] (sigmoid)
// Block ownership (uneven so gates finish FAST):
//   blocks 64..87  : 12 rows each (covers all gates)
//   blocks 88..255 : 22 rows each
#define NROWV 3852
#define NGPROD 23       // blocks 64..86 contain gate rows (row0 < 268)
#define MLDS 24         // mem rows 0..23 LDS-resident in A2 blocks (96 KB = WaL region)

struct P {
  const float *Wk_r,*bk_r,*Wb_r,*bb_r,*Wg_r,*bg_r,*Ws_r,*bs_r,*Wga_r,*bga_r;
  const float *Wk_w,*bk_w,*Wb_w,*bb_w,*Wg_w,*bg_w,*Ws_w,*bs_w,*Wga_w,*bga_w;
  const float *We,*be,*Wa,*ba,*W_r2i,*b_r2i,*Wih,*bih,*Whh,*bhh,*Who,*bho;
  const float *x, *mem0;
  float *outs, *wr, *ww, *memOut, *h;
  float *hT4, *YT, *GY, *xiT4, *W_r2iT, *memT;
  int *gateCnt;
  int *bkCnt;          // 4 group counters (B done), 64-int spacing (separate cachelines)
};

__device__ __forceinline__ float sigmf(float x){ return 1.f/(1.f+expf(-x)); }
__device__ __forceinline__ float splusf(float x){ return fmaxf(x,0.f) + log1pf(expf(-fabsf(x))); }
__device__ __forceinline__ float4 ld4(const float* p){ return *reinterpret_cast<const float4*>(p); }
__device__ __forceinline__ void st4(float* p, float4 v){ *reinterpret_cast<float4*>(p) = v; }
__device__ __forceinline__ float wredsum(float v){
  #pragma unroll
  for (int o = 32; o; o >>= 1) v += __shfl_xor(v, o);
  return v;
}
__device__ __forceinline__ float wredmax(float v){
  #pragma unroll
  for (int o = 32; o; o >>= 1) v = fmaxf(v, __shfl_xor(v, o));
  return v;
}
__device__ __forceinline__ float dot4f(float a, float4 wv, float4 vv){
  return fmaf(wv.x, vv.x, fmaf(wv.y, vv.y, fmaf(wv.z, vv.z, fmaf(wv.w, vv.w, a))));
}

// wait for all 4 B-group counters >= target, then block-wide acquire
__device__ __forceinline__ void bk_wait(const P& p, int target, int tid) {
  if (tid < 4) {
    while (__hip_atomic_load(&p.bkCnt[tid*64], __ATOMIC_RELAXED, __HIP_MEMORY_SCOPE_AGENT) < target)
      __builtin_amdgcn_s_sleep(2);
  }
  __syncthreads();
  __builtin_amdgcn_fence(__ATOMIC_ACQUIRE, "agent");
}

// gate row descriptor (g in [0,268))
__device__ __forceinline__ const float* gate_src(const P& p, int g, float& bias, int& act) {
  if (g < 140) {
    const int head = (g >= 70);
    const int q = g - head*70;
    if (q < 64)  { bias = (head?p.bk_w:p.bk_r)[q]; act=0; return (head?p.Wk_w:p.Wk_r)+(size_t)q*HH; }
    if (q == 64) { bias = (head?p.bb_w:p.bb_r)[0]; act=1; return head?p.Wb_w:p.Wb_r; }
    if (q == 65) { bias = (head?p.bg_w:p.bg_r)[0]; act=2; return head?p.Wg_w:p.Wg_r; }
    if (q < 69)  { bias = (head?p.bs_w:p.bs_r)[q-66]; act=5; return (head?p.Ws_w:p.Ws_r)+(size_t)(q-66)*HH; }
    bias = (head?p.bga_w:p.bga_r)[0]; act=4; return head?p.Wga_w:p.Wga_r;
  }
  if (g < 204) { const int m=g-140; bias=p.be[m]; act=2; return p.We+(size_t)m*HH; }
  const int m = g-204; bias=p.ba[m]; act=0; return p.Wa+(size_t)m*HH;
}

// -------- GEMV phase: K-split 4kg x 4rg x NRL rows, LDS weights --------
template<int NRL, int RPB>
__device__ void gemvA(const P& p, const float* WaL, float* SH, int t, int row0,
                      bool gateprod, int tid, int wv, int lane) {
  // dataflow: all B(t-1) done -> hT4 ready, YT/GY free to overwrite
  bk_wait(p, 64*t, tid);
  const int kg = wv & 3, rg = wv >> 2;
  const int kbase = kg*64;
  const int RPAD = 4*NRL;
  const float* hp = p.hT4 + lane*4;
  float acc[NRL];
  #pragma unroll
  for (int rl = 0; rl < NRL; ++rl) acc[rl] = 0.f;
  for (int kk = 0; kk < 64; kk += 4) {
    float4 hb0 = ld4(hp + (size_t)(kbase+kk+0)*256);
    float4 hb1 = ld4(hp + (size_t)(kbase+kk+1)*256);
    float4 hb2 = ld4(hp + (size_t)(kbase+kk+2)*256);
    float4 hb3 = ld4(hp + (size_t)(kbase+kk+3)*256);
    #pragma unroll
    for (int rl = 0; rl < NRL; ++rl) {
      const float* wl = WaL + (size_t)(rg*NRL+rl)*1024;
      acc[rl] = dot4f(acc[rl], ld4(wl + (kbase+kk+0)*4), hb0);
      acc[rl] = dot4f(acc[rl], ld4(wl + (kbase+kk+1)*4), hb1);
      acc[rl] = dot4f(acc[rl], ld4(wl + (kbase+kk+2)*4), hb2);
      acc[rl] = dot4f(acc[rl], ld4(wl + (kbase+kk+3)*4), hb3);
    }
  }
  #pragma unroll
  for (int rl = 0; rl < NRL; ++rl)
    SH[(kg*RPAD + rg*NRL + rl)*64 + lane] = acc[rl];
  __syncthreads();
  for (int idx = tid; idx < RPAD*64; idx += 1024) {
    const int rloc = idx >> 6, b = idx & 63;
    if (rloc >= RPB) continue;
    const int r = row0 + rloc;
    if (r >= NROWV) continue;
    float v = SH[(0*RPAD+rloc)*64+b] + SH[(1*RPAD+rloc)*64+b]
            + SH[(2*RPAD+rloc)*64+b] + SH[(3*RPAD+rloc)*64+b];
    if (r < 268) {
      float bias; int act;
      gate_src(p, r, bias, act);
      v += bias;
      if (act==0) v = tanhf(v);
      else if (act==1) v = splusf(v);
      else if (act==2) v = sigmf(v);
      else if (act==4) v = 1.f + splusf(v);
      p.GY[(size_t)r*64 + b] = v;
    } else if (r < 3340) {
      const int rr = r - 268;
      p.YT[(size_t)rr*64 + b] = v + p.bhh[rr];
    } else if (t >= 1) {
      const int o = r - 3340;
      p.outs[((size_t)b*TT + (t-1))*OO + o] = sigmf(v + p.bho[o]);
    }
  }
  __syncthreads();
  if (gateprod && tid == 0) {
    __builtin_amdgcn_fence(__ATOMIC_RELEASE, "agent");
    __hip_atomic_fetch_add(p.gateCnt, 1, __ATOMIC_RELAXED, __HIP_MEMORY_SCOPE_AGENT);
  }
}

// -------- per-head addressing, thread-owns-n (n = tid) --------
__device__ void head_addr(const P& p, float* SH, int head, float sim, float rown2,
                          int b, int tid, int wv, int lane) {
  float* scal = SH+320; float* red = SH+336; float* wg_s = SH+384;
  float* wdst = SH + (head ? 2432 : 1408);
  const float beta=scal[head*4+0], g=scal[head*4+1], gam=scal[head*4+2], kn=scal[head*4+3];
  const float s0=scal[8+head*3+0], s1=scal[8+head*3+1], s2=scal[8+head*3+2];
  float pp = beta * sim / (kn * sqrtf(rown2) + EPSF);
  float mx = wredmax(pp);
  if (lane == 0) red[wv] = mx;
  __syncthreads();
  mx = red[0];
  #pragma unroll
  for (int i = 1; i < 16; ++i) mx = fmaxf(mx, red[i]);
  pp = expf(pp - mx);
  float sm = wredsum(pp);
  if (lane == 0) red[16+wv] = sm;
  __syncthreads();
  sm = 0.f;
  #pragma unroll
  for (int i = 0; i < 16; ++i) sm += red[16+i];
  float* wbuf = (head ? p.ww : p.wr) + (size_t)b*NN;
  float wp = wbuf[tid];
  float wg = g * (pp / sm) + (1.f - g) * wp;
  wg_s[tid] = wg;
  __syncthreads();
  float wt = s0*wg_s[(tid+NN-1)&(NN-1)] + s1*wg + s2*wg_s[(tid+1)&(NN-1)];
  float w = powf(wt + 1e-12f, gam);
  float ps = wredsum(w);
  if (lane == 0) red[wv] = ps;
  __syncthreads();
  ps = 0.f;
  #pragma unroll
  for (int i = 0; i < 16; ++i) ps += red[i];
  w = w / (ps + EPSF);
  wbuf[tid] = w;
  wdst[tid] = w;
  __syncthreads();
}

// -------- A2 (blocks 0..63): wait gates -> mem chain (LDS rows 0..23 + global) -> rinxi --------
__device__ void phaseA2(const P& p, float* memL, float* SH, int t, int b,
                        int tid, int wv, int lane) {
  float* kr_s = SH;        float* kw_s = SH+64;
  float* e_s  = SH+128;    float* a_s  = SH+192;
  float* r_s  = SH+256;    float* scal = SH+320;
  float* wA   = SH+1408;   float* wB   = SH+2432;
  // wait for gate rows of step t (23 fast producers; gates waited on bk themselves)
  if (tid == 0) {
    const int target = NGPROD*(t+1);
    while (__hip_atomic_load(p.gateCnt, __ATOMIC_RELAXED, __HIP_MEMORY_SCOPE_AGENT) < target)
      __builtin_amdgcn_s_sleep(4);
  }
  __syncthreads();
  __builtin_amdgcn_fence(__ATOMIC_ACQUIRE, "agent");
  // gather activated gates
  if (tid < 268) {
    const int g = tid;
    float v = p.GY[(size_t)g*64 + b];
    if (g < 64) kr_s[g] = v;
    else if (g == 64) scal[0] = v;
    else if (g == 65) scal[1] = v;
    else if (g < 69)  scal[8 + g-66] = v;
    else if (g == 69) scal[2] = v;
    else if (g < 134) kw_s[g-70] = v;
    else if (g == 134) scal[4] = v;
    else if (g == 135) scal[5] = v;
    else if (g < 139) scal[11 + g-136] = v;
    else if (g == 139) scal[6] = v;
    else if (g < 204) e_s[g-140] = v;
    else a_s[g-204] = v;
  }
  __syncthreads();
  if (wv == 0) { float v = kr_s[lane]; float q = wredsum(v*v); if (lane==0) scal[3] = sqrtf(q); }
  else if (wv == 1) { float v = kw_s[lane]; float q = wredsum(v*v); if (lane==0) scal[7] = sqrtf(q); }
  else if (wv == 2 && lane < 2) {
    float* sv = &scal[8 + lane*3];
    float s0v=sv[0], s1v=sv[1], s2v=sv[2];
    float mxs = fmaxf(s0v, fmaxf(s1v, s2v));
    float e0=expf(s0v-mxs), e1=expf(s1v-mxs), e2=expf(s2v-mxs);
    float inv = 1.f/(e0+e1+e2);
    sv[0]=e0*inv; sv[1]=e1*inv; sv[2]=e2*inv;
  }
  __syncthreads();
  // sim pass: rows 0..23 from LDS, 24..63 from global memT (thread owns n = tid)
  float* mb = p.memT + (size_t)b*MM*NN;
  float simr=0.f, simw=0.f, qq=0.f;
  #pragma unroll
  for (int m = 0; m < MLDS; ++m) {
    float v = memL[m*NN + tid];
    simr = fmaf(kr_s[m], v, simr);
    simw = fmaf(kw_s[m], v, simw);
    qq   = fmaf(v, v, qq);
  }
  #pragma unroll 8
  for (int m = MLDS; m < MM; ++m) {
    float v = mb[(size_t)m*NN + tid];
    simr = fmaf(kr_s[m], v, simr);
    simw = fmaf(kw_s[m], v, simw);
    qq   = fmaf(v, v, qq);
  }
  head_addr(p, SH, 0, simr, qq, b, tid, wv, lane);
  head_addr(p, SH, 1, simw, qq, b, tid, wv, lane);
  // read + erase/add, wave owns 4 m rows (waves 0..5: LDS rows; 6..15: global)
  float4 wAr[4], wBr[4];
  #pragma unroll
  for (int c = 0; c < 4; ++c) { wAr[c] = ld4(&wA[c*256 + lane*4]); wBr[c] = ld4(&wB[c*256 + lane*4]); }
  if (wv < 6) {
    #pragma unroll
    for (int i = 0; i < 4; ++i) {
      const int m = wv*4 + i;
      const float em = e_s[m], am = a_s[m];
      float* rowp = memL + m*NN;
      float racc = 0.f;
      #pragma unroll
      for (int c = 0; c < 4; ++c) {
        float4 v = ld4(rowp + c*256 + lane*4);
        racc = dot4f(racc, wAr[c], v);
        float4 nv;
        nv.x = fmaf(wBr[c].x, fmaf(-em, v.x, am), v.x);
        nv.y = fmaf(wBr[c].y, fmaf(-em, v.y, am), v.y);
        nv.z = fmaf(wBr[c].z, fmaf(-em, v.z, am), v.z);
        nv.w = fmaf(wBr[c].w, fmaf(-em, v.w, am), v.w);
        st4(rowp + c*256 + lane*4, nv);
      }
      racc = wredsum(racc);
      if (lane == 0) r_s[m] = racc;
    }
  } else {
    #pragma unroll
    for (int i = 0; i < 4; ++i) {
      const int m = wv*4 + i;
      const float em = e_s[m], am = a_s[m];
      float* rowp = mb + (size_t)m*NN;
      float racc = 0.f;
      #pragma unroll
      for (int c = 0; c < 4; ++c) {
        float4 v = ld4(rowp + c*256 + lane*4);
        racc = dot4f(racc, wAr[c], v);
        float4 nv;
        nv.x = fmaf(wBr[c].x, fmaf(-em, v.x, am), v.x);
        nv.y = fmaf(wBr[c].y, fmaf(-em, v.y, am), v.y);
        nv.z = fmaf(wBr[c].z, fmaf(-em, v.z, am), v.z);
        nv.w = fmaf(wBr[c].w, fmaf(-em, v.w, am), v.w);
        st4(rowp + c*256 + lane*4, nv);
      }
      racc = wredsum(racc);
      if (lane == 0) r_s[m] = racc;
    }
  }
  __syncthreads();
  // rinxi -> xiT4
  if (tid < II) {
    float acc = p.b_r2i[tid];
    #pragma unroll 8
    for (int m = 0; m < MM; ++m) acc = fmaf(p.W_r2iT[(size_t)m*II + tid], r_s[m], acc);
    float xv = p.x[((size_t)b*TT + t)*II + tid];
    float xi = fmaxf(xv + fmaxf(acc, 0.f), 0.f);
    p.xiT4[((size_t)(tid>>2)*64 + b)*4 + (tid&3)] = xi;
  }
  __syncthreads();
}

// -------- phase B: gi GEMV K-split + fused GRU, all 256 blocks --------
__device__ void phaseB(const P& p, const float* WbL, float* SH, int blk,
                       int tid, int wv, int lane) {
  const int kg = wv & 3, rg = wv >> 2;
  const int j0 = blk * 4;
  const int kbase = kg*32;
  const float* xp = p.xiT4 + lane*4;
  float acc[3] = {0,0,0};
  for (int kk = 0; kk < 32; kk += 4) {
    float4 x0 = ld4(xp + (size_t)(kbase+kk+0)*256);
    float4 x1 = ld4(xp + (size_t)(kbase+kk+1)*256);
    float4 x2 = ld4(xp + (size_t)(kbase+kk+2)*256);
    float4 x3 = ld4(xp + (size_t)(kbase+kk+3)*256);
    #pragma unroll
    for (int rl = 0; rl < 3; ++rl) {
      const float* wl = WbL + (size_t)(rg*3+rl)*512;
      acc[rl] = dot4f(acc[rl], ld4(wl + (kbase+kk+0)*4), x0);
      acc[rl] = dot4f(acc[rl], ld4(wl + (kbase+kk+1)*4), x1);
      acc[rl] = dot4f(acc[rl], ld4(wl + (kbase+kk+2)*4), x2);
      acc[rl] = dot4f(acc[rl], ld4(wl + (kbase+kk+3)*4), x3);
    }
  }
  #pragma unroll
  for (int rl = 0; rl < 3; ++rl)
    SH[(kg*12 + rg*3 + rl)*64 + lane] = acc[rl];
  __syncthreads();
  float* gi = SH + 3072;
  if (tid < 768) {
    const int rr = tid >> 6, b = tid & 63;
    const int row = (rr>>2)*1024 + j0 + (rr&3);
    gi[rr*64 + b] = SH[(0*12+rr)*64+b] + SH[(1*12+rr)*64+b]
                  + SH[(2*12+rr)*64+b] + SH[(3*12+rr)*64+b] + p.bih[row];
  }
  __syncthreads();
  if (tid < 256) {
    const int jl = tid >> 6, b = tid & 63;
    const int j = j0 + jl;
    float gir = gi[(0*4 + jl)*64 + b];
    float giz = gi[(1*4 + jl)*64 + b];
    float gin = gi[(2*4 + jl)*64 + b];
    float ghr = p.YT[(size_t)j*64 + b];
    float ghz = p.YT[(size_t)(1024+j)*64 + b];
    float ghn = p.YT[(size_t)(2048+j)*64 + b];
    float hold = p.hT4[((size_t)(j>>2)*64 + b)*4 + (j&3)];
    float rr_ = sigmf(gir + ghr);
    float zz  = sigmf(giz + ghz);
    float nn_ = tanhf(gin + rr_*ghn);
    float hn = (1.f - zz)*nn_ + zz*hold;
    p.hT4[((size_t)(j>>2)*64 + b)*4 + (j&3)] = hn;   // persistent state only
  }
  __syncthreads();
  // B done for this block: release + count (group = blk>>6)
  if (tid == 0) {
    __builtin_amdgcn_fence(__ATOMIC_RELEASE, "agent");
    __hip_atomic_fetch_add(&p.bkCnt[(blk>>6)*64], 1, __ATOMIC_RELAXED, __HIP_MEMORY_SCOPE_AGENT);
  }
}

// -------- prologue/epilogue mem transposes (blocks 0..63), 16 waves --------
__device__ void memT_build(const P& p, float* tile, int b, int wv, int lane) {
  for (int nt = 0; nt < 16; ++nt) {
    const int n0 = nt*64;
    __syncthreads();
    #pragma unroll
    for (int i = 0; i < 4; ++i) {
      const int nn = wv*4 + i;
      tile[nn*65 + lane] = p.mem0[((size_t)b*NN + n0 + nn)*MM + lane];
    }
    __syncthreads();
    #pragma unroll
    for (int i = 0; i < 4; ++i) {
      const int m = wv*4 + i;
      p.memT[((size_t)b*MM + m)*NN + n0 + lane] = tile[lane*65 + m];
    }
  }
}

__device__ void memT_out(const P& p, float* tile, int b, int wv, int lane) {
  for (int nt = 0; nt < 16; ++nt) {
    const int n0 = nt*64;
    __syncthreads();
    #pragma unroll
    for (int i = 0; i < 4; ++i) {
      const int m = wv*4 + i;
      tile[lane*65 + m] = p.memT[((size_t)b*MM + m)*NN + n0 + lane];
    }
    __syncthreads();
    #pragma unroll
    for (int i = 0; i < 4; ++i) {
      const int nn = wv*4 + i;
      p.memOut[((size_t)b*NN + n0 + nn)*MM + lane] = tile[nn*65 + lane];
    }
  }
}

// ---------------- single persistent cooperative kernel ----------------
__global__ __launch_bounds__(1024, 4) void ntm_all(P p) {
  __shared__ float smem[36864];          // 144 KB: WaL|memL 96K | WbL 24K | SH 24K
  float* WaL  = smem;                    // GEMV blocks: 24*1024 weight rows
  float* memL = smem;                    // A2 blocks: mem rows 0..23 (96 KB)
  float* WbL  = smem + 24576;            // 12*512
  float* SH   = smem + 30720;            // 6144
  cg::grid_group grid = cg::this_grid();
  const int blk = blockIdx.x, tid = threadIdx.x;
  const int wv = tid >> 6, lane = tid & 63;
  const bool isGate = (blk >= 64 && blk < 88);
  const int row0 = isGate ? (blk-64)*12 : 288 + (blk-88)*22;
  const bool gateprod = (blk >= 64 && blk <= 86);   // 23 producers own rows < 268

  // ---- prologue ----
  if (wv < 6) {                          // WbL: 12 Wih rows (all blocks)
    #pragma unroll
    for (int q = 0; q < 2; ++q) {
      const int rr = wv*2 + q;
      const int row = (rr>>2)*1024 + blk*4 + (rr&3);
      float* wl = WbL + rr*512;
      const float* src = p.Wih + (size_t)row*II;
      #pragma unroll
      for (int c = 0; c < 2; ++c) st4(wl + c*256 + lane*4, ld4(src + c*256 + lane*4));
    }
  }
  if (blk >= 64) {                       // WaL
    const int npad = isGate ? 12 : 24;
    const int nval = isGate ? 12 : 22;
    for (int rloc = wv; rloc < npad; rloc += 16) {
      const int r = row0 + rloc;
      float* wl = WaL + (size_t)rloc*1024;
      const bool valid = (rloc < nval) && (r < NROWV);
      if (valid) {
        float bias; int act;
        const float* src = (r < 268) ? gate_src(p, r, bias, act)
                         : (r < 3340) ? p.Whh + (size_t)(r-268)*HH
                         : p.Who + (size_t)(r-3340)*HH;
        #pragma unroll
        for (int c = 0; c < 4; ++c) st4(wl + c*256 + lane*4, ld4(src + c*256 + lane*4));
      } else {
        const float4 z = make_float4(0.f,0.f,0.f,0.f);
        #pragma unroll
        for (int c = 0; c < 4; ++c) st4(wl + c*256 + lane*4, z);
      }
    }
  } else {                               // blocks 0..63: state builds
    memT_build(p, SH, blk, wv, lane);
    __syncthreads();
    // pin mem rows 0..23 into LDS (block-local)
    {
      const float* src = p.memT + (size_t)blk*MM*NN;
      for (int i = tid*4; i < MLDS*NN; i += 4096)
        st4(&memL[i], ld4(src + i));
    }
    if (tid < 256) {
      float4 v = ld4(p.h + (size_t)blk*HH + tid*4);
      st4(p.hT4 + ((size_t)tid*64 + blk)*4, v);
    }
    if (tid < II) p.W_r2iT[(size_t)blk*II + tid] = p.W_r2i[(size_t)tid*MM + blk];
    __syncthreads();
  }
  grid.sync();

  // ---- time loop: 1 grid sync + producer-count flags (B -> next A) ----
  for (int t = 0; t < TT; ++t) {
    if (blk < 64) phaseA2(p, memL, SH, t, blk, tid, wv, lane);
    else if (isGate) gemvA<3,12>(p, WaL, SH, t, row0, gateprod, tid, wv, lane);
    else gemvA<6,22>(p, WaL, SH, t, row0, false, tid, wv, lane);
    grid.sync();                         // A(t) done everywhere -> B(t) may read YT/xi
    phaseB(p, WbL, SH, blk, tid, wv, lane);
    // no grid sync: next A waits on bkCnt (all 4 groups = all 256 B blocks)
  }

  // ---- epilogue: outs[T-1] + final h + mem writeback + back-transpose ----
  if (blk >= 88) {
    gemvA<6,22>(p, WaL, SH, TT, row0, false, tid, wv, lane);
  } else if (blk < 64) {
    bk_wait(p, 64*TT, tid);              // all B(TT-1) done -> hT4 final
    if (tid < 256) {                     // final h from hT4
      float4 v = ld4(p.hT4 + ((size_t)tid*64 + blk)*4);
      st4(p.h + (size_t)blk*HH + tid*4, v);
    }
    // write LDS-resident mem rows back to memT, then transpose out
    {
      float* dst = p.memT + (size_t)blk*MM*NN;
      for (int i = tid*4; i < MLDS*NN; i += 4096)
        st4(dst + i, ld4(&memL[i]));
    }
    __syncthreads();
    memT_out(p, SH, blk, wv, lane);
  }
}

extern "C" void kernel_launch(void* const* d_in, const int* in_sizes, int n_in,
                              void* d_out, int out_size, void* d_ws, size_t ws_size,
                              hipStream_t stream) {
  const float* x    = (const float*)d_in[0];
  const float* h0   = (const float*)d_in[1];
  const float* wr0  = (const float*)d_in[2];
  const float* ww0  = (const float*)d_in[3];
  const float* mem0 = (const float*)d_in[4];
  P p;
  int i = 5;
  p.Wk_r  = (const float*)d_in[i++]; p.bk_r  = (const float*)d_in[i++];
  p.Wb_r  = (const float*)d_in[i++]; p.bb_r  = (const float*)d_in[i++];
  p.Wg_r  = (const float*)d_in[i++]; p.bg_r  = (const float*)d_in[i++];
  p.Ws_r  = (const float*)d_in[i++]; p.bs_r  = (const float*)d_in[i++];
  p.Wga_r = (const float*)d_in[i++]; p.bga_r = (const float*)d_in[i++];
  p.Wk_w  = (const float*)d_in[i++]; p.bk_w  = (const float*)d_in[i++];
  p.Wb_w  = (const float*)d_in[i++]; p.bb_w  = (const float*)d_in[i++];
  p.Wg_w  = (const float*)d_in[i++]; p.bg_w  = (const float*)d_in[i++];
  p.Ws_w  = (const float*)d_in[i++]; p.bs_w  = (const float*)d_in[i++];
  p.Wga_w = (const float*)d_in[i++]; p.bga_w = (const float*)d_in[i++];
  p.We    = (const float*)d_in[i++]; p.be    = (const float*)d_in[i++];
  p.Wa    = (const float*)d_in[i++]; p.ba    = (const float*)d_in[i++];
  p.W_r2i = (const float*)d_in[i++]; p.b_r2i = (const float*)d_in[i++];
  p.Wih   = (const float*)d_in[i++]; p.bih   = (const float*)d_in[i++];
  p.Whh   = (const float*)d_in[i++]; p.bhh   = (const float*)d_in[i++];
  p.Who   = (const float*)d_in[i++]; p.bho   = (const float*)d_in[i++];
  p.x = x; p.mem0 = mem0;

  float* out = (float*)d_out;
  p.outs   = out;                                  // (B,T,O)
  p.h      = out + (size_t)BB*TT*OO;               // (B,H) final h
  p.wr     = p.h + (size_t)BB*HH;                  // (B,N)
  p.ww     = p.wr + (size_t)BB*NN;                 // (B,N)
  p.memOut = p.ww + (size_t)BB*NN;                 // (B,N,M)

  int* cnts = (int*)d_ws;                          // 4 KB flag region
  p.gateCnt = cnts;                                // [0]
  p.bkCnt   = cnts + 64;                           // groups at +64,+128,+192,+256
  float* ws = (float*)d_ws + 1024;
  p.hT4    = ws;  ws += (size_t)256*64*4;          // 256 KB
  p.YT     = ws;  ws += (size_t)3072*64;           // 768 KB
  p.GY     = ws;  ws += (size_t)268*64;            // 67 KB
  p.xiT4   = ws;  ws += (size_t)128*64*4;          // 128 KB
  p.W_r2iT = ws;  ws += (size_t)MM*II;             // 128 KB
  p.memT   = ws;  ws += (size_t)BB*MM*NN;          // 16 MB   (total ~17.4 MB)

  hipMemsetAsync(d_ws, 0, 4096, stream);
  hipMemcpyAsync(p.h,  h0,  (size_t)BB*HH*sizeof(float), hipMemcpyDeviceToDevice, stream);
  hipMemcpyAsync(p.wr, wr0, (size_t)BB*NN*sizeof(float), hipMemcpyDeviceToDevice, stream);
  hipMemcpyAsync(p.ww, ww0, (size_t)BB*NN*sizeof(float), hipMemcpyDeviceToDevice, stream);

  void* args[] = { (void*)&p };
  hipLaunchCooperativeKernel((const void*)ntm_all, dim3(256), dim3(1024), args, 0, stream);
}

// Round 15
// 2929.437 us; speedup vs baseline: 1.6548x; 1.6548x over previous
//
#include <hip/hip_runtime.h>
#include <hip/hip_cooperative_groups.h>
#include <math.h>

namespace cg = cooperative_groups;

#define BB 64
#define TT 32
#define II 512
#define HH 1024
#define OO 512
#define NN 1024
#define MM 64
#define EPSF 1e-8f

// virtual GEMV row space (K=1024, all dot h):
//   [0,268) gates -> GY ; [268,3340) Whh -> YT ; [3340,3852) Who -> outs[t-1]
// blocks 64..87: 12 rows each (all gates, fast); blocks 88..255: 22 rows each
#define NROWV 3852
#define NGPROD 23
#define MLDS 24         // mem rows 0..23 LDS-resident in A2 blocks

struct P {
  const float *Wk_r,*bk_r,*Wb_r,*bb_r,*Wg_r,*bg_r,*Ws_r,*bs_r,*Wga_r,*bga_r;
  const float *Wk_w,*bk_w,*Wb_w,*bb_w,*Wg_w,*bg_w,*Ws_w,*bs_w,*Wga_w,*bga_w;
  const float *We,*be,*Wa,*ba,*W_r2i,*b_r2i,*Wih,*bih,*Whh,*bhh,*Who,*bho;
  const float *x, *mem0;
  float *outs, *wr, *ww, *memOut, *h;
  float *hT4, *YT, *GY, *xiT4, *W_r2iT, *memT;
  int *gateCnt, *aCnt, *xCnt, *bkCnt;   // counters, 32-int (128B) spacing
};

__device__ __forceinline__ float sigmf(float x){ return 1.f/(1.f+expf(-x)); }
__device__ __forceinline__ float splusf(float x){ return fmaxf(x,0.f) + log1pf(expf(-fabsf(x))); }
__device__ __forceinline__ float4 ld4(const float* p){ return *reinterpret_cast<const float4*>(p); }
__device__ __forceinline__ void st4(float* p, float4 v){ *reinterpret_cast<float4*>(p) = v; }
__device__ __forceinline__ float wredsum(float v){
  #pragma unroll
  for (int o = 32; o; o >>= 1) v += __shfl_xor(v, o);
  return v;
}
__device__ __forceinline__ float wredmax(float v){
  #pragma unroll
  for (int o = 32; o; o >>= 1) v = fmaxf(v, __shfl_xor(v, o));
  return v;
}
__device__ __forceinline__ float dot4f(float a, float4 wv, float4 vv){
  return fmaf(wv.x, vv.x, fmaf(wv.y, vv.y, fmaf(wv.z, vv.z, fmaf(wv.w, vv.w, a))));
}

// ---- agent-coherent (LLC) loads: sc0 sc1 bypass stale L1/L2, NO global invalidate ----
__device__ __forceinline__ void ld4x4_sc1(const float* p0, const float* p1,
                                          const float* p2, const float* p3,
                                          float4& a, float4& b, float4& c, float4& d){
  asm volatile(
    "global_load_dwordx4 %0, %4, off sc0 sc1\n\t"
    "global_load_dwordx4 %1, %5, off sc0 sc1\n\t"
    "global_load_dwordx4 %2, %6, off sc0 sc1\n\t"
    "global_load_dwordx4 %3, %7, off sc0 sc1\n\t"
    "s_waitcnt vmcnt(0)"
    : "=&v"(a), "=&v"(b), "=&v"(c), "=&v"(d)
    : "v"(p0), "v"(p1), "v"(p2), "v"(p3));
}
__device__ __forceinline__ float ld1_sc1(const float* p){
  float r;
  asm volatile("global_load_dword %0, %1, off sc0 sc1\n\ts_waitcnt vmcnt(0)"
               : "=&v"(r) : "v"(p));
  return r;
}
__device__ __forceinline__ void ld1x3_sc1(const float* p0, const float* p1, const float* p2,
                                          float& a, float& b, float& c){
  asm volatile(
    "global_load_dword %0, %3, off sc0 sc1\n\t"
    "global_load_dword %1, %4, off sc0 sc1\n\t"
    "global_load_dword %2, %5, off sc0 sc1\n\t"
    "s_waitcnt vmcnt(0)"
    : "=&v"(a), "=&v"(b), "=&v"(c)
    : "v"(p0), "v"(p1), "v"(p2));
}

// spin-waits WITHOUT acquire fence (consumers use sc1 loads instead)
__device__ __forceinline__ void bk_wait_nf(const P& p, int target, int tid) {
  if (tid < 4) {
    while (__hip_atomic_load(&p.bkCnt[tid*32], __ATOMIC_RELAXED, __HIP_MEMORY_SCOPE_AGENT) < target)
      __builtin_amdgcn_s_sleep(2);
  }
  __syncthreads();
}
__device__ __forceinline__ void bk_wait_acq(const P& p, int target, int tid) {
  if (tid < 4) {
    while (__hip_atomic_load(&p.bkCnt[tid*32], __ATOMIC_RELAXED, __HIP_MEMORY_SCOPE_AGENT) < target)
      __builtin_amdgcn_s_sleep(2);
  }
  __syncthreads();
  __builtin_amdgcn_fence(__ATOMIC_ACQUIRE, "agent");
}

// gate row descriptor (g in [0,268))
__device__ __forceinline__ const float* gate_src(const P& p, int g, float& bias, int& act) {
  if (g < 140) {
    const int head = (g >= 70);
    const int q = g - head*70;
    if (q < 64)  { bias = (head?p.bk_w:p.bk_r)[q]; act=0; return (head?p.Wk_w:p.Wk_r)+(size_t)q*HH; }
    if (q == 64) { bias = (head?p.bb_w:p.bb_r)[0]; act=1; return head?p.Wb_w:p.Wb_r; }
    if (q == 65) { bias = (head?p.bg_w:p.bg_r)[0]; act=2; return head?p.Wg_w:p.Wg_r; }
    if (q < 69)  { bias = (head?p.bs_w:p.bs_r)[q-66]; act=5; return (head?p.Ws_w:p.Ws_r)+(size_t)(q-66)*HH; }
    bias = (head?p.bga_w:p.bga_r)[0]; act=4; return head?p.Wga_w:p.Wga_r;
  }
  if (g < 204) { const int m=g-140; bias=p.be[m]; act=2; return p.We+(size_t)m*HH; }
  const int m = g-204; bias=p.ba[m]; act=0; return p.Wa+(size_t)m*HH;
}

// -------- GEMV phase: K-split 4kg x 4rg x NRL rows, LDS weights, sc1 h-reads --------
template<int NRL, int RPB>
__device__ void gemvA(const P& p, const float* WaL, float* SH, int t, int row0,
                      bool gateprod, int tid, int wv, int lane) {
  bk_wait_nf(p, 64*t, tid);              // all B(t-1) done
  const int kg = wv & 3, rg = wv >> 2;
  const int kbase = kg*64;
  const int RPAD = 4*NRL;
  const float* hp = p.hT4 + lane*4;
  float acc[NRL];
  #pragma unroll
  for (int rl = 0; rl < NRL; ++rl) acc[rl] = 0.f;
  for (int kk = 0; kk < 64; kk += 4) {
    float4 hb0, hb1, hb2, hb3;
    ld4x4_sc1(hp + (size_t)(kbase+kk+0)*256, hp + (size_t)(kbase+kk+1)*256,
              hp + (size_t)(kbase+kk+2)*256, hp + (size_t)(kbase+kk+3)*256,
              hb0, hb1, hb2, hb3);
    #pragma unroll
    for (int rl = 0; rl < NRL; ++rl) {
      const float* wl = WaL + (size_t)(rg*NRL+rl)*1024;
      acc[rl] = dot4f(acc[rl], ld4(wl + (kbase+kk+0)*4), hb0);
      acc[rl] = dot4f(acc[rl], ld4(wl + (kbase+kk+1)*4), hb1);
      acc[rl] = dot4f(acc[rl], ld4(wl + (kbase+kk+2)*4), hb2);
      acc[rl] = dot4f(acc[rl], ld4(wl + (kbase+kk+3)*4), hb3);
    }
  }
  #pragma unroll
  for (int rl = 0; rl < NRL; ++rl)
    SH[(kg*RPAD + rg*NRL + rl)*64 + lane] = acc[rl];
  __syncthreads();
  for (int idx = tid; idx < RPAD*64; idx += 1024) {
    const int rloc = idx >> 6, b = idx & 63;
    if (rloc >= RPB) continue;
    const int r = row0 + rloc;
    if (r >= NROWV) continue;
    float v = SH[(0*RPAD+rloc)*64+b] + SH[(1*RPAD+rloc)*64+b]
            + SH[(2*RPAD+rloc)*64+b] + SH[(3*RPAD+rloc)*64+b];
    if (r < 268) {
      float bias; int act;
      gate_src(p, r, bias, act);
      v += bias;
      if (act==0) v = tanhf(v);
      else if (act==1) v = splusf(v);
      else if (act==2) v = sigmf(v);
      else if (act==4) v = 1.f + splusf(v);
      p.GY[(size_t)r*64 + b] = v;
    } else if (r < 3340) {
      const int rr = r - 268;
      p.YT[(size_t)rr*64 + b] = v + p.bhh[rr];
    } else if (t >= 1) {
      const int o = r - 3340;
      p.outs[((size_t)b*TT + (t-1))*OO + o] = sigmf(v + p.bho[o]);
    }
  }
  __syncthreads();
  if (tid == 0) {
    __builtin_amdgcn_fence(__ATOMIC_RELEASE, "agent");   // writeback (no invalidate)
    if (gateprod)
      __hip_atomic_fetch_add(p.gateCnt, 1, __ATOMIC_RELAXED, __HIP_MEMORY_SCOPE_AGENT);
    __hip_atomic_fetch_add(p.aCnt, 1, __ATOMIC_RELAXED, __HIP_MEMORY_SCOPE_AGENT);
  }
}

// -------- per-head addressing, thread-owns-n (n = tid) --------
__device__ void head_addr(const P& p, float* SH, int head, float sim, float rown2,
                          int b, int tid, int wv, int lane) {
  float* scal = SH+320; float* red = SH+336; float* wg_s = SH+384;
  float* wdst = SH + (head ? 2432 : 1408);
  const float beta=scal[head*4+0], g=scal[head*4+1], gam=scal[head*4+2], kn=scal[head*4+3];
  const float s0=scal[8+head*3+0], s1=scal[8+head*3+1], s2=scal[8+head*3+2];
  float pp = beta * sim / (kn * sqrtf(rown2) + EPSF);
  float mx = wredmax(pp);
  if (lane == 0) red[wv] = mx;
  __syncthreads();
  mx = red[0];
  #pragma unroll
  for (int i = 1; i < 16; ++i) mx = fmaxf(mx, red[i]);
  pp = expf(pp - mx);
  float sm = wredsum(pp);
  if (lane == 0) red[16+wv] = sm;
  __syncthreads();
  sm = 0.f;
  #pragma unroll
  for (int i = 0; i < 16; ++i) sm += red[16+i];
  float* wbuf = (head ? p.ww : p.wr) + (size_t)b*NN;
  float wp = wbuf[tid];
  float wg = g * (pp / sm) + (1.f - g) * wp;
  wg_s[tid] = wg;
  __syncthreads();
  float wt = s0*wg_s[(tid+NN-1)&(NN-1)] + s1*wg + s2*wg_s[(tid+1)&(NN-1)];
  float w = powf(wt + 1e-12f, gam);
  float ps = wredsum(w);
  if (lane == 0) red[wv] = ps;
  __syncthreads();
  ps = 0.f;
  #pragma unroll
  for (int i = 0; i < 16; ++i) ps += red[i];
  w = w / (ps + EPSF);
  wbuf[tid] = w;
  wdst[tid] = w;
  __syncthreads();
}

// -------- A2 (blocks 0..63): wait gates -> mem chain (LDS + L2-warm global) -> rinxi --------
__device__ void phaseA2(const P& p, float* memL, float* SH, int t, int b,
                        int tid, int wv, int lane) {
  float* kr_s = SH;        float* kw_s = SH+64;
  float* e_s  = SH+128;    float* a_s  = SH+192;
  float* r_s  = SH+256;    float* scal = SH+320;
  float* wA   = SH+1408;   float* wB   = SH+2432;
  if (tid == 0) {
    const int target = NGPROD*(t+1);
    while (__hip_atomic_load(p.gateCnt, __ATOMIC_RELAXED, __HIP_MEMORY_SCOPE_AGENT) < target)
      __builtin_amdgcn_s_sleep(4);
  }
  __syncthreads();                       // no acquire fence: GY read via sc1
  if (tid < 268) {
    const int g = tid;
    float v = ld1_sc1(p.GY + (size_t)g*64 + b);
    if (g < 64) kr_s[g] = v;
    else if (g == 64) scal[0] = v;
    else if (g == 65) scal[1] = v;
    else if (g < 69)  scal[8 + g-66] = v;
    else if (g == 69) scal[2] = v;
    else if (g < 134) kw_s[g-70] = v;
    else if (g == 134) scal[4] = v;
    else if (g == 135) scal[5] = v;
    else if (g < 139) scal[11 + g-136] = v;
    else if (g == 139) scal[6] = v;
    else if (g < 204) e_s[g-140] = v;
    else a_s[g-204] = v;
  }
  __syncthreads();
  if (wv == 0) { float v = kr_s[lane]; float q = wredsum(v*v); if (lane==0) scal[3] = sqrtf(q); }
  else if (wv == 1) { float v = kw_s[lane]; float q = wredsum(v*v); if (lane==0) scal[7] = sqrtf(q); }
  else if (wv == 2 && lane < 2) {
    float* sv = &scal[8 + lane*3];
    float s0v=sv[0], s1v=sv[1], s2v=sv[2];
    float mxs = fmaxf(s0v, fmaxf(s1v, s2v));
    float e0=expf(s0v-mxs), e1=expf(s1v-mxs), e2=expf(s2v-mxs);
    float inv = 1.f/(e0+e1+e2);
    sv[0]=e0*inv; sv[1]=e1*inv; sv[2]=e2*inv;
  }
  __syncthreads();
  // sim pass: rows 0..23 LDS, 24..63 from (L2-warm) private memT
  float* mb = p.memT + (size_t)b*MM*NN;
  float simr=0.f, simw=0.f, qq=0.f;
  #pragma unroll
  for (int m = 0; m < MLDS; ++m) {
    float v = memL[m*NN + tid];
    simr = fmaf(kr_s[m], v, simr);
    simw = fmaf(kw_s[m], v, simw);
    qq   = fmaf(v, v, qq);
  }
  #pragma unroll 8
  for (int m = MLDS; m < MM; ++m) {
    float v = mb[(size_t)m*NN + tid];
    simr = fmaf(kr_s[m], v, simr);
    simw = fmaf(kw_s[m], v, simw);
    qq   = fmaf(v, v, qq);
  }
  head_addr(p, SH, 0, simr, qq, b, tid, wv, lane);
  head_addr(p, SH, 1, simw, qq, b, tid, wv, lane);
  float4 wAr[4], wBr[4];
  #pragma unroll
  for (int c = 0; c < 4; ++c) { wAr[c] = ld4(&wA[c*256 + lane*4]); wBr[c] = ld4(&wB[c*256 + lane*4]); }
  if (wv < 6) {
    #pragma unroll
    for (int i = 0; i < 4; ++i) {
      const int m = wv*4 + i;
      const float em = e_s[m], am = a_s[m];
      float* rowp = memL + m*NN;
      float racc = 0.f;
      #pragma unroll
      for (int c = 0; c < 4; ++c) {
        float4 v = ld4(rowp + c*256 + lane*4);
        racc = dot4f(racc, wAr[c], v);
        float4 nv;
        nv.x = fmaf(wBr[c].x, fmaf(-em, v.x, am), v.x);
        nv.y = fmaf(wBr[c].y, fmaf(-em, v.y, am), v.y);
        nv.z = fmaf(wBr[c].z, fmaf(-em, v.z, am), v.z);
        nv.w = fmaf(wBr[c].w, fmaf(-em, v.w, am), v.w);
        st4(rowp + c*256 + lane*4, nv);
      }
      racc = wredsum(racc);
      if (lane == 0) r_s[m] = racc;
    }
  } else {
    #pragma unroll
    for (int i = 0; i < 4; ++i) {
      const int m = wv*4 + i;
      const float em = e_s[m], am = a_s[m];
      float* rowp = mb + (size_t)m*NN;
      float racc = 0.f;
      #pragma unroll
      for (int c = 0; c < 4; ++c) {
        float4 v = ld4(rowp + c*256 + lane*4);
        racc = dot4f(racc, wAr[c], v);
        float4 nv;
        nv.x = fmaf(wBr[c].x, fmaf(-em, v.x, am), v.x);
        nv.y = fmaf(wBr[c].y, fmaf(-em, v.y, am), v.y);
        nv.z = fmaf(wBr[c].z, fmaf(-em, v.z, am), v.z);
        nv.w = fmaf(wBr[c].w, fmaf(-em, v.w, am), v.w);
        st4(rowp + c*256 + lane*4, nv);
      }
      racc = wredsum(racc);
      if (lane == 0) r_s[m] = racc;
    }
  }
  __syncthreads();
  if (tid < II) {
    float acc = p.b_r2i[tid];
    #pragma unroll 8
    for (int m = 0; m < MM; ++m) acc = fmaf(p.W_r2iT[(size_t)m*II + tid], r_s[m], acc);
    float xv = p.x[((size_t)b*TT + t)*II + tid];
    float xi = fmaxf(xv + fmaxf(acc, 0.f), 0.f);
    p.xiT4[((size_t)(tid>>2)*64 + b)*4 + (tid&3)] = xi;
  }
  __syncthreads();
  if (tid == 0) {
    __builtin_amdgcn_fence(__ATOMIC_RELEASE, "agent");
    __hip_atomic_fetch_add(p.xCnt, 1, __ATOMIC_RELAXED, __HIP_MEMORY_SCOPE_AGENT);
  }
}

// -------- phase B: gi GEMV K-split + fused GRU, all 256 blocks --------
__device__ void phaseB(const P& p, const float* WbL, float* SH, int blk, int t,
                       int tid, int wv, int lane) {
  // dataflow: all gemvA(t) done (YT) + all A2(t) done (xi) — no acquire, sc1 reads
  if (tid == 0) {
    const int ta = 192*(t+1);
    while (__hip_atomic_load(p.aCnt, __ATOMIC_RELAXED, __HIP_MEMORY_SCOPE_AGENT) < ta)
      __builtin_amdgcn_s_sleep(2);
  } else if (tid == 1) {
    const int tx = 64*(t+1);
    while (__hip_atomic_load(p.xCnt, __ATOMIC_RELAXED, __HIP_MEMORY_SCOPE_AGENT) < tx)
      __builtin_amdgcn_s_sleep(2);
  }
  __syncthreads();
  const int kg = wv & 3, rg = wv >> 2;
  const int j0 = blk * 4;
  const int kbase = kg*32;
  const float* xp = p.xiT4 + lane*4;
  float acc[3] = {0,0,0};
  for (int kk = 0; kk < 32; kk += 4) {
    float4 x0, x1, x2, x3;
    ld4x4_sc1(xp + (size_t)(kbase+kk+0)*256, xp + (size_t)(kbase+kk+1)*256,
              xp + (size_t)(kbase+kk+2)*256, xp + (size_t)(kbase+kk+3)*256,
              x0, x1, x2, x3);
    #pragma unroll
    for (int rl = 0; rl < 3; ++rl) {
      const float* wl = WbL + (size_t)(rg*3+rl)*512;
      acc[rl] = dot4f(acc[rl], ld4(wl + (kbase+kk+0)*4), x0);
      acc[rl] = dot4f(acc[rl], ld4(wl + (kbase+kk+1)*4), x1);
      acc[rl] = dot4f(acc[rl], ld4(wl + (kbase+kk+2)*4), x2);
      acc[rl] = dot4f(acc[rl], ld4(wl + (kbase+kk+3)*4), x3);
    }
  }
  #pragma unroll
  for (int rl = 0; rl < 3; ++rl)
    SH[(kg*12 + rg*3 + rl)*64 + lane] = acc[rl];
  __syncthreads();
  float* gi = SH + 3072;
  if (tid < 768) {
    const int rr = tid >> 6, b = tid & 63;
    const int row = (rr>>2)*1024 + j0 + (rr&3);
    gi[rr*64 + b] = SH[(0*12+rr)*64+b] + SH[(1*12+rr)*64+b]
                  + SH[(2*12+rr)*64+b] + SH[(3*12+rr)*64+b] + p.bih[row];
  }
  __syncthreads();
  if (tid < 256) {
    const int jl = tid >> 6, b = tid & 63;
    const int j = j0 + jl;
    float gir = gi[(0*4 + jl)*64 + b];
    float giz = gi[(1*4 + jl)*64 + b];
    float gin = gi[(2*4 + jl)*64 + b];
    float ghr, ghz, ghn;
    ld1x3_sc1(p.YT + (size_t)j*64 + b, p.YT + (size_t)(1024+j)*64 + b,
              p.YT + (size_t)(2048+j)*64 + b, ghr, ghz, ghn);
    float hold = p.hT4[((size_t)(j>>2)*64 + b)*4 + (j&3)];   // own write, cached OK
    float rr_ = sigmf(gir + ghr);
    float zz  = sigmf(giz + ghz);
    float nn_ = tanhf(gin + rr_*ghn);
    float hn = (1.f - zz)*nn_ + zz*hold;
    p.hT4[((size_t)(j>>2)*64 + b)*4 + (j&3)] = hn;
  }
  __syncthreads();
  if (tid == 0) {
    __builtin_amdgcn_fence(__ATOMIC_RELEASE, "agent");
    __hip_atomic_fetch_add(&p.bkCnt[(blk>>6)*32], 1, __ATOMIC_RELAXED, __HIP_MEMORY_SCOPE_AGENT);
  }
}

// -------- prologue/epilogue mem transposes (blocks 0..63), 16 waves --------
__device__ void memT_build(const P& p, float* tile, int b, int wv, int lane) {
  for (int nt = 0; nt < 16; ++nt) {
    const int n0 = nt*64;
    __syncthreads();
    #pragma unroll
    for (int i = 0; i < 4; ++i) {
      const int nn = wv*4 + i;
      tile[nn*65 + lane] = p.mem0[((size_t)b*NN + n0 + nn)*MM + lane];
    }
    __syncthreads();
    #pragma unroll
    for (int i = 0; i < 4; ++i) {
      const int m = wv*4 + i;
      p.memT[((size_t)b*MM + m)*NN + n0 + lane] = tile[lane*65 + m];
    }
  }
}

__device__ void memT_out(const P& p, float* tile, int b, int wv, int lane) {
  for (int nt = 0; nt < 16; ++nt) {
    const int n0 = nt*64;
    __syncthreads();
    #pragma unroll
    for (int i = 0; i < 4; ++i) {
      const int m = wv*4 + i;
      tile[lane*65 + m] = p.memT[((size_t)b*MM + m)*NN + n0 + lane];
    }
    __syncthreads();
    #pragma unroll
    for (int i = 0; i < 4; ++i) {
      const int nn = wv*4 + i;
      p.memOut[((size_t)b*NN + n0 + nn)*MM + lane] = tile[nn*65 + lane];
    }
  }
}

// ---------------- single persistent cooperative kernel ----------------
__global__ __launch_bounds__(1024, 4) void ntm_all(P p) {
  __shared__ float smem[36864];          // 144 KB: WaL|memL 96K | WbL 24K | SH 24K
  float* WaL  = smem;
  float* memL = smem;
  float* WbL  = smem + 24576;
  float* SH   = smem + 30720;
  cg::grid_group grid = cg::this_grid();
  const int blk = blockIdx.x, tid = threadIdx.x;
  const int wv = tid >> 6, lane = tid & 63;
  const bool isGate = (blk >= 64 && blk < 88);
  const int row0 = isGate ? (blk-64)*12 : 288 + (blk-88)*22;
  const bool gateprod = (blk >= 64 && blk <= 86);

  // ---- prologue ----
  if (wv < 6) {
    #pragma unroll
    for (int q = 0; q < 2; ++q) {
      const int rr = wv*2 + q;
      const int row = (rr>>2)*1024 + blk*4 + (rr&3);
      float* wl = WbL + rr*512;
      const float* src = p.Wih + (size_t)row*II;
      #pragma unroll
      for (int c = 0; c < 2; ++c) st4(wl + c*256 + lane*4, ld4(src + c*256 + lane*4));
    }
  }
  if (blk >= 64) {
    const int npad = isGate ? 12 : 24;
    const int nval = isGate ? 12 : 22;
    for (int rloc = wv; rloc < npad; rloc += 16) {
      const int r = row0 + rloc;
      float* wl = WaL + (size_t)rloc*1024;
      const bool valid = (rloc < nval) && (r < NROWV);
      if (valid) {
        float bias; int act;
        const float* src = (r < 268) ? gate_src(p, r, bias, act)
                         : (r < 3340) ? p.Whh + (size_t)(r-268)*HH
                         : p.Who + (size_t)(r-3340)*HH;
        #pragma unroll
        for (int c = 0; c < 4; ++c) st4(wl + c*256 + lane*4, ld4(src + c*256 + lane*4));
      } else {
        const float4 z = make_float4(0.f,0.f,0.f,0.f);
        #pragma unroll
        for (int c = 0; c < 4; ++c) st4(wl + c*256 + lane*4, z);
      }
    }
  } else {
    memT_build(p, SH, blk, wv, lane);
    __syncthreads();
    {
      const float* src = p.memT + (size_t)blk*MM*NN;
      for (int i = tid*4; i < MLDS*NN; i += 4096)
        st4(&memL[i], ld4(src + i));
    }
    if (tid < 256) {
      float4 v = ld4(p.h + (size_t)blk*HH + tid*4);
      st4(p.hT4 + ((size_t)tid*64 + blk)*4, v);
    }
    if (tid < II) p.W_r2iT[(size_t)blk*II + tid] = p.W_r2i[(size_t)tid*MM + blk];
    __syncthreads();
  }
  grid.sync();

  // ---- time loop: ZERO acquire fences; dataflow counters + sc1 loads ----
  for (int t = 0; t < TT; ++t) {
    if (blk < 64) phaseA2(p, memL, SH, t, blk, tid, wv, lane);
    else if (isGate) gemvA<3,12>(p, WaL, SH, t, row0, gateprod, tid, wv, lane);
    else gemvA<6,22>(p, WaL, SH, t, row0, false, tid, wv, lane);
    phaseB(p, WbL, SH, blk, t, tid, wv, lane);
  }

  // ---- epilogue ----
  if (blk >= 88) {
    gemvA<6,22>(p, WaL, SH, TT, row0, false, tid, wv, lane);
  } else if (blk < 64) {
    bk_wait_acq(p, 64*TT, tid);          // one-time full acquire for final state
    if (tid < 256) {
      float4 v = ld4(p.hT4 + ((size_t)tid*64 + blk)*4);
      st4(p.h + (size_t)blk*HH + tid*4, v);
    }
    {
      float* dst = p.memT + (size_t)blk*MM*NN;
      for (int i = tid*4; i < MLDS*NN; i += 4096)
        st4(dst + i, ld4(&memL[i]));
    }
    __syncthreads();
    memT_out(p, SH, blk, wv, lane);
  }
}

extern "C" void kernel_launch(void* const* d_in, const int* in_sizes, int n_in,
                              void* d_out, int out_size, void* d_ws, size_t ws_size,
                              hipStream_t stream) {
  const float* x    = (const float*)d_in[0];
  const float* h0   = (const float*)d_in[1];
  const float* wr0  = (const float*)d_in[2];
  const float* ww0  = (const float*)d_in[3];
  const float* mem0 = (const float*)d_in[4];
  P p;
  int i = 5;
  p.Wk_r  = (const float*)d_in[i++]; p.bk_r  = (const float*)d_in[i++];
  p.Wb_r  = (const float*)d_in[i++]; p.bb_r  = (const float*)d_in[i++];
  p.Wg_r  = (const float*)d_in[i++]; p.bg_r  = (const float*)d_in[i++];
  p.Ws_r  = (const float*)d_in[i++]; p.bs_r  = (const float*)d_in[i++];
  p.Wga_r = (const float*)d_in[i++]; p.bga_r = (const float*)d_in[i++];
  p.Wk_w  = (const float*)d_in[i++]; p.bk_w  = (const float*)d_in[i++];
  p.Wb_w  = (const float*)d_in[i++]; p.bb_w  = (const float*)d_in[i++];
  p.Wg_w  = (const float*)d_in[i++]; p.bg_w  = (const float*)d_in[i++];
  p.Ws_w  = (const float*)d_in[i++]; p.bs_w  = (const float*)d_in[i++];
  p.Wga_w = (const float*)d_in[i++]; p.bga_w = (const float*)d_in[i++];
  p.We    = (const float*)d_in[i++]; p.be    = (const float*)d_in[i++];
  p.Wa    = (const float*)d_in[i++]; p.ba    = (const float*)d_in[i++];
  p.W_r2i = (const float*)d_in[i++]; p.b_r2i = (const float*)d_in[i++];
  p.Wih   = (const float*)d_in[i++]; p.bih   = (const float*)d_in[i++];
  p.Whh   = (const float*)d_in[i++]; p.bhh   = (const float*)d_in[i++];
  p.Who   = (const float*)d_in[i++]; p.bho   = (const float*)d_in[i++];
  p.x = x; p.mem0 = mem0;

  float* out = (float*)d_out;
  p.outs   = out;                                  // (B,T,O)
  p.h      = out + (size_t)BB*TT*OO;               // (B,H) final h
  p.wr     = p.h + (size_t)BB*HH;                  // (B,N)
  p.ww     = p.wr + (size_t)BB*NN;                 // (B,N)
  p.memOut = p.ww + (size_t)BB*NN;                 // (B,N,M)

  int* cnts = (int*)d_ws;                          // 4 KB flag region
  p.gateCnt = cnts +   0;
  p.aCnt    = cnts +  256;
  p.xCnt    = cnts +  512;
  p.bkCnt   = cnts +  768;                         // groups at +0,+32,+64,+96
  float* ws = (float*)d_ws + 1024;
  p.hT4    = ws;  ws += (size_t)256*64*4;          // 256 KB
  p.YT     = ws;  ws += (size_t)3072*64;           // 768 KB
  p.GY     = ws;  ws += (size_t)268*64;            // 67 KB
  p.xiT4   = ws;  ws += (size_t)128*64*4;          // 128 KB
  p.W_r2iT = ws;  ws += (size_t)MM*II;             // 128 KB
  p.memT   = ws;  ws += (size_t)BB*MM*NN;          // 16 MB   (total ~17.4 MB)

  hipMemsetAsync(d_ws, 0, 4096, stream);
  hipMemcpyAsync(p.h,  h0,  (size_t)BB*HH*sizeof(float), hipMemcpyDeviceToDevice, stream);
  hipMemcpyAsync(p.wr, wr0, (size_t)BB*NN*sizeof(float), hipMemcpyDeviceToDevice, stream);
  hipMemcpyAsync(p.ww, ww0, (size_t)BB*NN*sizeof(float), hipMemcpyDeviceToDevice, stream);

  void* args[] = { (void*)&p };
  hipLaunchCooperativeKernel((const void*)ntm_all, dim3(256), dim3(1024), args, 0, stream);
}